// Round 8
// baseline (484.708 us; speedup 1.0000x reference)
//
#include <hip/hip_runtime.h>
#include <hip/hip_fp8.h>

#define DIM 128
#define LN_EPS 1e-5f

typedef __attribute__((ext_vector_type(8))) short s16x8;   // 8 bf16 in 4 VGPRs
typedef __attribute__((ext_vector_type(4))) float f32x4;
typedef __attribute__((ext_vector_type(2))) float f32x2;
typedef __attribute__((ext_vector_type(4))) unsigned int u32x4;
typedef __attribute__((ext_vector_type(2))) unsigned int u32x2;

__device__ __forceinline__ unsigned short f2bf(float f) {
    unsigned u = __float_as_uint(f);
    unsigned r = u + 0x7fffu + ((u >> 16) & 1u);   // round-to-nearest-even
    return (unsigned short)(r >> 16);
}
__device__ __forceinline__ float bf2f(unsigned short b) {
    return __uint_as_float(((unsigned)b) << 16);
}
__device__ __forceinline__ unsigned char f2fp8(float f) {
    return (unsigned char)__hip_cvt_float_to_fp8(f, __HIP_SATFINITE, __HIP_E4M3);
}
// accumulate 4 fp8 bytes (linear col order) into a[0..3]
__device__ __forceinline__ void acc_fp8x4(float* a, unsigned v) {
    f32x2 lo = __builtin_amdgcn_cvt_pk_f32_fp8(v, false);  // bytes 0,1
    f32x2 hi = __builtin_amdgcn_cvt_pk_f32_fp8(v, true);   // bytes 2,3
    a[0] += lo[0]; a[1] += lo[1]; a[2] += hi[0]; a[3] += hi[1];
}

// ---------------- CSR build ----------------

__global__ void count_deg(const int* __restrict__ dst, int E, int* __restrict__ counts) {
    int i = blockIdx.x * 256 + threadIdx.x;
    if (i < E) atomicAdd(&counts[dst[i]], 1);
}

// single-block fused scan: thread t owns counts[t*C, t*C+C); 2 barriers total
__global__ __launch_bounds__(1024) void scan_fused(const int* __restrict__ counts, int n, int E,
                                                   int* __restrict__ rowptr,
                                                   int* __restrict__ cursor,
                                                   float* __restrict__ dinv) {
    int t = threadIdx.x;
    const int C = (n + 1023) / 1024;
    int base = t * C;
    int s = 0;
    for (int j = 0; j < C; ++j) {
        int i = base + j;
        if (i < n) s += counts[i];
    }
    int lane = t & 63, wv = t >> 6;
    int incl = s;
#pragma unroll
    for (int off = 1; off < 64; off <<= 1) {
        int tmp = __shfl_up(incl, off, 64);
        if (lane >= off) incl += tmp;
    }
    __shared__ int wsum[16];
    if (lane == 63) wsum[wv] = incl;
    __syncthreads();
    int wofs = 0;
#pragma unroll
    for (int w = 0; w < 16; ++w) wofs += (w < wv) ? wsum[w] : 0;
    int excl = wofs + incl - s;
    for (int j = 0; j < C; ++j) {
        int i = base + j;
        if (i < n) {
            int v = counts[i];
            rowptr[i] = excl;
            cursor[i] = excl;
            dinv[i] = 1.0f / (float)((v > 1) ? v : 1);
            excl += v;
        }
    }
    if (t == 0) rowptr[n] = E;
}

__global__ void fill_csr(const int* __restrict__ src, const int* __restrict__ dst, int E,
                         int* __restrict__ cursor, int* __restrict__ srcidx) {
    int i = blockIdx.x * 256 + threadIdx.x;
    if (i < E) {
        int p = atomicAdd(&cursor[dst[i]], 1);
        srcidx[p] = src[i];
    }
}

// ---------------- weight conversion: f32 row-major -> bf16 transposed ----------------

__global__ __launch_bounds__(256) void cvt_weights(const float* __restrict__ in_w,
                                                   const float* __restrict__ w1,
                                                   const float* __restrict__ w2,
                                                   unsigned short* __restrict__ wt, int L) {
    int mat = blockIdx.x >> 3, part = blockIdx.x & 7;
    const float* src;
    if (mat == 0) src = in_w;
    else if (mat <= L) src = w1 + (size_t)(mat - 1) * DIM * DIM;
    else src = w2 + (size_t)(mat - 1 - L) * DIM * DIM;
    unsigned short* dst = wt + (size_t)mat * DIM * DIM;
    int base = part * 2048 + threadIdx.x;
#pragma unroll
    for (int j = 0; j < 8; ++j) {
        int i = base + j * 256;
        int k = i >> 7, n = i & 127;
        dst[n * DIM + k] = f2bf(src[i]);
    }
}

// ---------------- input projection (MFMA, col-split): hb/h8 = x @ in_w + in_b ----
// block = 16 rows, 4 waves; wave s computes cols [s*32, s*32+32). No LDS, no barrier.

__global__ __launch_bounds__(256) void gemm_bias_mfma(const float* __restrict__ x,
                                                      const unsigned short* __restrict__ Wt,
                                                      const float* __restrict__ bias,
                                                      unsigned short* __restrict__ hb,
                                                      unsigned char* __restrict__ h8, int N) {
    int tid = threadIdx.x;
    int s = tid >> 6, lane = tid & 63;
    int quad = lane >> 4, l16 = lane & 15;
    int r0 = blockIdx.x * 16;
    int cs = s * 32;
    int arow = r0 + l16;
    bool av = arow < N;

    f32x4 acc[2];
    acc[0] = (f32x4){0.f, 0.f, 0.f, 0.f};
    acc[1] = (f32x4){0.f, 0.f, 0.f, 0.f};

    const float4* xp = (const float4*)(x + ((size_t)(av ? arow : 0) << 7)) + quad * 2;
#pragma unroll
    for (int k0 = 0; k0 < 128; k0 += 32) {
        s16x8 a = {0, 0, 0, 0, 0, 0, 0, 0};
        if (av) {
            float4 f0 = xp[k0 / 4];
            float4 f1 = xp[k0 / 4 + 1];
            a[0] = (short)f2bf(f0.x); a[1] = (short)f2bf(f0.y);
            a[2] = (short)f2bf(f0.z); a[3] = (short)f2bf(f0.w);
            a[4] = (short)f2bf(f1.x); a[5] = (short)f2bf(f1.y);
            a[6] = (short)f2bf(f1.z); a[7] = (short)f2bf(f1.w);
        }
        s16x8 b0 = *(const s16x8*)(Wt + ((size_t)(cs + l16) << 7) + quad * 8 + k0);
        s16x8 b1 = *(const s16x8*)(Wt + ((size_t)(cs + 16 + l16) << 7) + quad * 8 + k0);
        acc[0] = __builtin_amdgcn_mfma_f32_16x16x32_bf16(a, b0, acc[0], 0, 0, 0);
        acc[1] = __builtin_amdgcn_mfma_f32_16x16x32_bf16(a, b1, acc[1], 0, 0, 0);
    }

#pragma unroll
    for (int c = 0; c < 2; ++c) {
        int col = cs + c * 16 + l16;
        float bv = bias[col];
#pragma unroll
        for (int reg = 0; reg < 4; ++reg) {
            int grow = r0 + quad * 4 + reg;
            if (grow < N) {
                float o = acc[c][reg] + bv;
                hb[((size_t)grow << 7) + col] = f2bf(o);
                h8[((size_t)grow << 7) + col] = f2fp8(o);
            }
        }
    }
}

// ---------------- fused layer (col-split, fp8 gather) ----------------
// block = 16 rows, 4 waves; wave s owns col-slice [s*32, s*32+32).
// Gather reads fp8 table (128 B/row = 1 cache line); residual reads bf16.

__global__ __launch_bounds__(256) void agg_mlp_ln(const unsigned short* __restrict__ hin,
                                                  const unsigned char* __restrict__ h8in,
                                                  const int* __restrict__ rowptr,
                                                  const int* __restrict__ srcidx,
                                                  const float* __restrict__ dinv,
                                                  const unsigned short* __restrict__ W1t,
                                                  const float* __restrict__ B1,
                                                  const unsigned short* __restrict__ W2t,
                                                  const float* __restrict__ B2,
                                                  const float* __restrict__ G,
                                                  const float* __restrict__ Bb,
                                                  unsigned short* __restrict__ hout,
                                                  unsigned char* __restrict__ h8out,
                                                  float* __restrict__ out_f32, int N) {
    __shared__ unsigned short M[16][132];   // +4 pad: conflict-free b128 A-frag reads
    __shared__ unsigned short P[16][132];
    __shared__ float s1p[4][16], s2p[4][16];

    int tid = threadIdx.x;
    int s = tid >> 6, lane = tid & 63;
    int quad = lane >> 4, l16 = lane & 15;
    int g = lane >> 2, li = lane & 3;       // gather: group g owns node r0+g
    int r0 = blockIdx.x * 16;
    int cs = s * 32;

    // ---- gather (fp8): lane li covers 8 cols (8 B) of wave's 32-col slice ----
    int nd = r0 + g;
    bool nv = nd < N;
    int e  = nv ? rowptr[nd] : 0;
    int ee = nv ? rowptr[nd + 1] : 0;

    float a0[8] = {0, 0, 0, 0, 0, 0, 0, 0};   // linear col order: a0[i] = col cs+li*8+i
    float a1[8] = {0, 0, 0, 0, 0, 0, 0, 0};
    const unsigned char* hsl = h8in + cs + li * 8;

    while (__any(e < ee)) {
        int myidx = (e + li < ee) ? srcidx[e + li] : 0;
        int i0 = __shfl(myidx, (g << 2) | 0, 64);
        int i1 = __shfl(myidx, (g << 2) | 1, 64);
        int i2 = __shfl(myidx, (g << 2) | 2, 64);
        int i3 = __shfl(myidx, (g << 2) | 3, 64);
        bool p0 = e < ee, p1 = e + 1 < ee, p2 = e + 2 < ee, p3 = e + 3 < ee;
        u32x2 v0, v1, v2, v3;
        if (p0) v0 = *(const u32x2*)(hsl + ((size_t)i0 << 7));
        if (p1) v1 = *(const u32x2*)(hsl + ((size_t)i1 << 7));
        if (p2) v2 = *(const u32x2*)(hsl + ((size_t)i2 << 7));
        if (p3) v3 = *(const u32x2*)(hsl + ((size_t)i3 << 7));
        if (p0) { acc_fp8x4(a0,     v0[0]); acc_fp8x4(a0 + 4, v0[1]); }
        if (p1) { acc_fp8x4(a1,     v1[0]); acc_fp8x4(a1 + 4, v1[1]); }
        if (p2) { acc_fp8x4(a0,     v2[0]); acc_fp8x4(a0 + 4, v2[1]); }
        if (p3) { acc_fp8x4(a1,     v3[0]); acc_fp8x4(a1 + 4, v3[1]); }
        e += 4;
    }

    {
        float di = nv ? dinv[nd] : 0.f;
        u32x4 o;
#pragma unroll
        for (int j = 0; j < 4; ++j) {
            unsigned lo = f2bf((a0[2 * j]     + a1[2 * j])     * di);
            unsigned hi = f2bf((a0[2 * j + 1] + a1[2 * j + 1]) * di);
            o[j] = lo | (hi << 16);
        }
        *(u32x4*)(&M[g][cs + li * 8]) = o;
    }
    __syncthreads();

    // ---- GEMM1: relu(m @ W1 + b1); wave computes 16 rows x 32 cols ----
    f32x4 acc[2];
    acc[0] = (f32x4){0.f, 0.f, 0.f, 0.f};
    acc[1] = (f32x4){0.f, 0.f, 0.f, 0.f};
#pragma unroll
    for (int k0 = 0; k0 < 128; k0 += 32) {
        s16x8 a = *(const s16x8*)(&M[l16][quad * 8 + k0]);
        s16x8 b0 = *(const s16x8*)(W1t + ((size_t)(cs + l16) << 7) + quad * 8 + k0);
        s16x8 b1 = *(const s16x8*)(W1t + ((size_t)(cs + 16 + l16) << 7) + quad * 8 + k0);
        acc[0] = __builtin_amdgcn_mfma_f32_16x16x32_bf16(a, b0, acc[0], 0, 0, 0);
        acc[1] = __builtin_amdgcn_mfma_f32_16x16x32_bf16(a, b1, acc[1], 0, 0, 0);
    }
#pragma unroll
    for (int c = 0; c < 2; ++c) {
        int col = cs + c * 16 + l16;
        float bv = B1[col];
#pragma unroll
        for (int reg = 0; reg < 4; ++reg) {
            float v = fmaxf(acc[c][reg] + bv, 0.f);
            P[quad * 4 + reg][col] = f2bf(v);
        }
    }
    __syncthreads();

    // ---- GEMM2: P @ W2 ----
    acc[0] = (f32x4){0.f, 0.f, 0.f, 0.f};
    acc[1] = (f32x4){0.f, 0.f, 0.f, 0.f};
#pragma unroll
    for (int k0 = 0; k0 < 128; k0 += 32) {
        s16x8 a = *(const s16x8*)(&P[l16][quad * 8 + k0]);
        s16x8 b0 = *(const s16x8*)(W2t + ((size_t)(cs + l16) << 7) + quad * 8 + k0);
        s16x8 b1 = *(const s16x8*)(W2t + ((size_t)(cs + 16 + l16) << 7) + quad * 8 + k0);
        acc[0] = __builtin_amdgcn_mfma_f32_16x16x32_bf16(a, b0, acc[0], 0, 0, 0);
        acc[1] = __builtin_amdgcn_mfma_f32_16x16x32_bf16(a, b1, acc[1], 0, 0, 0);
    }

    // ---- epilogue: residual + LN (cross-wave row sums via LDS partials) ----
    float z[2][4];
    float ps1[4] = {0, 0, 0, 0}, ps2[4] = {0, 0, 0, 0};
#pragma unroll
    for (int c = 0; c < 2; ++c) {
        int col = cs + c * 16 + l16;
        float b2v = B2[col];
#pragma unroll
        for (int reg = 0; reg < 4; ++reg) {
            int grow = r0 + quad * 4 + reg;
            float hv = (grow < N) ? bf2f(hin[((size_t)grow << 7) + col]) : 0.f;
            float zz = acc[c][reg] + b2v + hv;
            z[c][reg] = zz;
            ps1[reg] += zz;
            ps2[reg] += zz * zz;
        }
    }
#pragma unroll
    for (int off = 1; off < 16; off <<= 1) {
#pragma unroll
        for (int reg = 0; reg < 4; ++reg) {
            ps1[reg] += __shfl_xor(ps1[reg], off, 64);
            ps2[reg] += __shfl_xor(ps2[reg], off, 64);
        }
    }
    if (l16 == 0) {
#pragma unroll
        for (int reg = 0; reg < 4; ++reg) {
            s1p[s][quad * 4 + reg] = ps1[reg];
            s2p[s][quad * 4 + reg] = ps2[reg];
        }
    }
    __syncthreads();

#pragma unroll
    for (int reg = 0; reg < 4; ++reg) {
        int row = quad * 4 + reg;
        float S1 = s1p[0][row] + s1p[1][row] + s1p[2][row] + s1p[3][row];
        float S2 = s2p[0][row] + s2p[1][row] + s2p[2][row] + s2p[3][row];
        float mean = S1 * (1.0f / 128.0f);
        float var = S2 * (1.0f / 128.0f) - mean * mean;
        float rs = rsqrtf(var + LN_EPS);
        int grow = r0 + row;
        if (grow < N) {
#pragma unroll
            for (int c = 0; c < 2; ++c) {
                int col = cs + c * 16 + l16;
                float o = (z[c][reg] - mean) * rs * G[col] + Bb[col];
                if (out_f32) {
                    out_f32[((size_t)grow << 7) + col] = o;   // last layer: f32 only
                } else {
                    hout[((size_t)grow << 7) + col] = f2bf(o);
                    h8out[((size_t)grow << 7) + col] = f2fp8(o);
                }
            }
        }
    }
}

// ---------------- launch ----------------

extern "C" void kernel_launch(void* const* d_in, const int* in_sizes, int n_in,
                              void* d_out, int out_size, void* d_ws, size_t ws_size,
                              hipStream_t stream) {
    const float* x    = (const float*)d_in[0];
    const int*   ei   = (const int*)d_in[1];
    const float* in_w = (const float*)d_in[2];
    const float* in_b = (const float*)d_in[3];
    const float* w1   = (const float*)d_in[4];
    const float* b1   = (const float*)d_in[5];
    const float* w2   = (const float*)d_in[6];
    const float* b2   = (const float*)d_in[7];
    const float* ln_g = (const float*)d_in[8];
    const float* ln_b = (const float*)d_in[9];

    const int N = in_sizes[0] / DIM;               // 50000
    const int E = in_sizes[1] / 2;                 // 640000
    const int LAYERS = in_sizes[4] / (DIM * DIM);  // 3

    const int* e_src = ei;
    const int* e_dst = ei + E;

    // workspace layout
    char* ws = (char*)d_ws;
    unsigned short* hb0    = (unsigned short*)ws;  ws += (size_t)N * DIM * 2;
    unsigned short* hb1    = (unsigned short*)ws;  ws += (size_t)N * DIM * 2;
    unsigned char*  h8a    = (unsigned char*)ws;   ws += (size_t)N * DIM;
    unsigned char*  h8b    = (unsigned char*)ws;   ws += (size_t)N * DIM;
    int*            counts = (int*)ws;             ws += (size_t)N * 4;
    int*            rowptr = (int*)ws;             ws += (size_t)(N + 1) * 4;
    int*            cursor = (int*)ws;             ws += (size_t)N * 4;
    float*          dinv   = (float*)ws;           ws += (size_t)N * 4;
    int*            srcidx = (int*)ws;             ws += (size_t)E * 4;
    unsigned short* wt     = (unsigned short*)ws;  ws += (size_t)(2 * LAYERS + 1) * DIM * DIM * 2;

    const int nMat = 2 * LAYERS + 1;

    // --- CSR build (deg is layer-invariant) + weight conversion ---
    (void)hipMemsetAsync(counts, 0, (size_t)N * 4, stream);
    count_deg<<<(E + 255) / 256, 256, 0, stream>>>(e_dst, E, counts);
    scan_fused<<<1, 1024, 0, stream>>>(counts, N, E, rowptr, cursor, dinv);
    fill_csr<<<(E + 255) / 256, 256, 0, stream>>>(e_src, e_dst, E, cursor, srcidx);
    cvt_weights<<<nMat * 8, 256, 0, stream>>>(in_w, w1, w2, wt, LAYERS);

    const unsigned short* in_wt = wt;
    const unsigned short* w1t   = wt + (size_t)DIM * DIM;
    const unsigned short* w2t   = wt + (size_t)(1 + LAYERS) * DIM * DIM;

    // --- input projection ---
    int tile_grid = (N + 15) / 16;
    gemm_bias_mfma<<<tile_grid, 256, 0, stream>>>(x, in_wt, in_b, hb0, h8a, N);

    // --- layers (ping-pong; gather reads pre-update fp8 table) ---
    unsigned short* hin  = hb0;  unsigned char* h8in  = h8a;
    unsigned short* hout = hb1;  unsigned char* h8out = h8b;
    for (int i = 0; i < LAYERS; ++i) {
        float* out = (i == LAYERS - 1) ? (float*)d_out : nullptr;
        agg_mlp_ln<<<tile_grid, 256, 0, stream>>>(hin, h8in, rowptr, srcidx, dinv,
                                                  w1t + (size_t)i * DIM * DIM, b1 + (size_t)i * DIM,
                                                  w2t + (size_t)i * DIM * DIM, b2 + (size_t)i * DIM,
                                                  ln_g + (size_t)i * DIM, ln_b + (size_t)i * DIM,
                                                  hout, h8out, out, N);
        unsigned short* t = hin; hin = hout; hout = t;
        unsigned char* t8 = h8in; h8in = h8out; h8out = t8;
    }
}

// Round 9
// 349.405 us; speedup vs baseline: 1.3872x; 1.3872x over previous
//
#include <hip/hip_runtime.h>
#include <hip/hip_fp8.h>

#define DIM 128
#define LN_EPS 1e-5f

typedef __attribute__((ext_vector_type(8))) short s16x8;   // 8 bf16 in 4 VGPRs
typedef __attribute__((ext_vector_type(4))) float f32x4;
typedef __attribute__((ext_vector_type(2))) float f32x2;
typedef __attribute__((ext_vector_type(4))) unsigned int u32x4;
typedef __attribute__((ext_vector_type(2))) unsigned int u32x2;

__device__ __forceinline__ unsigned short f2bf(float f) {
    unsigned u = __float_as_uint(f);
    unsigned r = u + 0x7fffu + ((u >> 16) & 1u);   // round-to-nearest-even
    return (unsigned short)(r >> 16);
}
__device__ __forceinline__ float bf2f(unsigned short b) {
    return __uint_as_float(((unsigned)b) << 16);
}
__device__ __forceinline__ unsigned char f2fp8(float f) {
    return (unsigned char)__hip_cvt_float_to_fp8(f, __HIP_SATFINITE, __HIP_E4M3);
}
// accumulate 4 fp8 bytes (linear col order) into a[0..3]
__device__ __forceinline__ void acc_fp8x4(float* a, unsigned v) {
    f32x2 lo = __builtin_amdgcn_cvt_pk_f32_fp8(v, false);  // bytes 0,1
    f32x2 hi = __builtin_amdgcn_cvt_pk_f32_fp8(v, true);   // bytes 2,3
    a[0] += lo[0]; a[1] += lo[1]; a[2] += hi[0]; a[3] += hi[1];
}

// ---------------- CSR build ----------------

__global__ void count_deg(const int* __restrict__ dst, int E, int* __restrict__ counts) {
    int i = blockIdx.x * 256 + threadIdx.x;
    if (i < E) atomicAdd(&counts[dst[i]], 1);
}

// --- multi-block scan, step 1: per-block partial sums (1024 elems / block of 256) ---
__global__ __launch_bounds__(256) void scan_partials(const int* __restrict__ counts, int n,
                                                     int* __restrict__ bsum) {
    int base = blockIdx.x * 1024 + threadIdx.x * 4;
    int s = 0;
#pragma unroll
    for (int j = 0; j < 4; ++j) {
        int i = base + j;
        if (i < n) s += counts[i];
    }
#pragma unroll
    for (int off = 32; off > 0; off >>= 1) s += __shfl_xor(s, off, 64);
    __shared__ int wsum[4];
    int lane = threadIdx.x & 63, wid = threadIdx.x >> 6;
    if (lane == 0) wsum[wid] = s;
    __syncthreads();
    if (threadIdx.x == 0) bsum[blockIdx.x] = wsum[0] + wsum[1] + wsum[2] + wsum[3];
}

// --- step 2: one wave scans the block sums ---
__global__ __launch_bounds__(64) void scan_bsums(const int* __restrict__ bsum,
                                                 int* __restrict__ bofs, int nb,
                                                 int* __restrict__ rowptr, int N, int E) {
    int lane = threadIdx.x;
    int carry = 0;
    for (int base = 0; base < nb; base += 64) {
        int v = (base + lane < nb) ? bsum[base + lane] : 0;
        int incl = v;
#pragma unroll
        for (int off = 1; off < 64; off <<= 1) {
            int t = __shfl_up(incl, off, 64);
            if (lane >= off) incl += t;
        }
        if (base + lane < nb) bofs[base + lane] = carry + incl - v;
        carry += __shfl(incl, 63, 64);
    }
    if (lane == 0) rowptr[N] = E;
}

// --- step 3: per-block scan with block offset; emit rowptr/cursor/dinv ---
__global__ __launch_bounds__(256) void scan_final(const int* __restrict__ counts, int n,
                                                  const int* __restrict__ bofs,
                                                  int* __restrict__ rowptr,
                                                  int* __restrict__ cursor,
                                                  float* __restrict__ dinv) {
    int base = blockIdx.x * 1024 + threadIdx.x * 4;
    int v[4];
#pragma unroll
    for (int j = 0; j < 4; ++j) {
        int i = base + j;
        v[j] = (i < n) ? counts[i] : 0;
    }
    int tsum = v[0] + v[1] + v[2] + v[3];
    int lane = threadIdx.x & 63, wid = threadIdx.x >> 6;
    int incl = tsum;
#pragma unroll
    for (int off = 1; off < 64; off <<= 1) {
        int t = __shfl_up(incl, off, 64);
        if (lane >= off) incl += t;
    }
    __shared__ int wsum[4];
    if (lane == 63) wsum[wid] = incl;
    __syncthreads();
    int wofs = 0;
    for (int w = 0; w < 4; ++w)
        if (w < wid) wofs += wsum[w];
    int excl = bofs[blockIdx.x] + wofs + (incl - tsum);
#pragma unroll
    for (int j = 0; j < 4; ++j) {
        int i = base + j;
        if (i < n) {
            rowptr[i] = excl;
            cursor[i] = excl;
            dinv[i] = 1.0f / (float)((v[j] > 1) ? v[j] : 1);
            excl += v[j];
        }
    }
}

__global__ void fill_csr(const int* __restrict__ src, const int* __restrict__ dst, int E,
                         int* __restrict__ cursor, int* __restrict__ srcidx) {
    int i = blockIdx.x * 256 + threadIdx.x;
    if (i < E) {
        int p = atomicAdd(&cursor[dst[i]], 1);
        srcidx[p] = src[i];
    }
}

// ---------------- weight conversion: f32 row-major -> bf16 transposed ----------------

__global__ __launch_bounds__(256) void cvt_weights(const float* __restrict__ in_w,
                                                   const float* __restrict__ w1,
                                                   const float* __restrict__ w2,
                                                   unsigned short* __restrict__ wt, int L) {
    int mat = blockIdx.x >> 3, part = blockIdx.x & 7;
    const float* src;
    if (mat == 0) src = in_w;
    else if (mat <= L) src = w1 + (size_t)(mat - 1) * DIM * DIM;
    else src = w2 + (size_t)(mat - 1 - L) * DIM * DIM;
    unsigned short* dst = wt + (size_t)mat * DIM * DIM;
    int base = part * 2048 + threadIdx.x;
#pragma unroll
    for (int j = 0; j < 8; ++j) {
        int i = base + j * 256;
        int k = i >> 7, n = i & 127;
        dst[n * DIM + k] = f2bf(src[i]);
    }
}

// ---------------- input projection (MFMA, col-split): hb/h8 = x @ in_w + in_b ----
// block = 16 rows, 4 waves; wave s computes cols [s*32, s*32+32). No LDS, no barrier.

__global__ __launch_bounds__(256) void gemm_bias_mfma(const float* __restrict__ x,
                                                      const unsigned short* __restrict__ Wt,
                                                      const float* __restrict__ bias,
                                                      unsigned short* __restrict__ hb,
                                                      unsigned char* __restrict__ h8, int N) {
    int tid = threadIdx.x;
    int s = tid >> 6, lane = tid & 63;
    int quad = lane >> 4, l16 = lane & 15;
    int r0 = blockIdx.x * 16;
    int cs = s * 32;
    int arow = r0 + l16;
    bool av = arow < N;

    f32x4 acc[2];
    acc[0] = (f32x4){0.f, 0.f, 0.f, 0.f};
    acc[1] = (f32x4){0.f, 0.f, 0.f, 0.f};

    const float4* xp = (const float4*)(x + ((size_t)(av ? arow : 0) << 7)) + quad * 2;
#pragma unroll
    for (int k0 = 0; k0 < 128; k0 += 32) {
        s16x8 a = {0, 0, 0, 0, 0, 0, 0, 0};
        if (av) {
            float4 f0 = xp[k0 / 4];
            float4 f1 = xp[k0 / 4 + 1];
            a[0] = (short)f2bf(f0.x); a[1] = (short)f2bf(f0.y);
            a[2] = (short)f2bf(f0.z); a[3] = (short)f2bf(f0.w);
            a[4] = (short)f2bf(f1.x); a[5] = (short)f2bf(f1.y);
            a[6] = (short)f2bf(f1.z); a[7] = (short)f2bf(f1.w);
        }
        s16x8 b0 = *(const s16x8*)(Wt + ((size_t)(cs + l16) << 7) + quad * 8 + k0);
        s16x8 b1 = *(const s16x8*)(Wt + ((size_t)(cs + 16 + l16) << 7) + quad * 8 + k0);
        acc[0] = __builtin_amdgcn_mfma_f32_16x16x32_bf16(a, b0, acc[0], 0, 0, 0);
        acc[1] = __builtin_amdgcn_mfma_f32_16x16x32_bf16(a, b1, acc[1], 0, 0, 0);
    }

#pragma unroll
    for (int c = 0; c < 2; ++c) {
        int col = cs + c * 16 + l16;
        float bv = bias[col];
#pragma unroll
        for (int reg = 0; reg < 4; ++reg) {
            int grow = r0 + quad * 4 + reg;
            if (grow < N) {
                float o = acc[c][reg] + bv;
                hb[((size_t)grow << 7) + col] = f2bf(o);
                h8[((size_t)grow << 7) + col] = f2fp8(o);
            }
        }
    }
}

// ---------------- fused layer (col-split, fp8 gather) ----------------
// block = 16 rows, 4 waves; wave s owns col-slice [s*32, s*32+32).
// Gather reads fp8 table (128 B/row = 1 cache line); residual reads bf16.

__global__ __launch_bounds__(256) void agg_mlp_ln(const unsigned short* __restrict__ hin,
                                                  const unsigned char* __restrict__ h8in,
                                                  const int* __restrict__ rowptr,
                                                  const int* __restrict__ srcidx,
                                                  const float* __restrict__ dinv,
                                                  const unsigned short* __restrict__ W1t,
                                                  const float* __restrict__ B1,
                                                  const unsigned short* __restrict__ W2t,
                                                  const float* __restrict__ B2,
                                                  const float* __restrict__ G,
                                                  const float* __restrict__ Bb,
                                                  unsigned short* __restrict__ hout,
                                                  unsigned char* __restrict__ h8out,
                                                  float* __restrict__ out_f32, int N) {
    __shared__ unsigned short M[16][132];   // +4 pad: conflict-free b128 A-frag reads
    __shared__ unsigned short P[16][132];
    __shared__ float s1p[4][16], s2p[4][16];

    int tid = threadIdx.x;
    int s = tid >> 6, lane = tid & 63;
    int quad = lane >> 4, l16 = lane & 15;
    int g = lane >> 2, li = lane & 3;       // gather: group g owns node r0+g
    int r0 = blockIdx.x * 16;
    int cs = s * 32;

    // ---- gather (fp8): lane li covers 8 cols (8 B) of wave's 32-col slice ----
    int nd = r0 + g;
    bool nv = nd < N;
    int e  = nv ? rowptr[nd] : 0;
    int ee = nv ? rowptr[nd + 1] : 0;

    float a0[8] = {0, 0, 0, 0, 0, 0, 0, 0};   // linear col order: a0[i] = col cs+li*8+i
    float a1[8] = {0, 0, 0, 0, 0, 0, 0, 0};
    const unsigned char* hsl = h8in + cs + li * 8;

    while (__any(e < ee)) {
        int myidx = (e + li < ee) ? srcidx[e + li] : 0;
        int i0 = __shfl(myidx, (g << 2) | 0, 64);
        int i1 = __shfl(myidx, (g << 2) | 1, 64);
        int i2 = __shfl(myidx, (g << 2) | 2, 64);
        int i3 = __shfl(myidx, (g << 2) | 3, 64);
        bool p0 = e < ee, p1 = e + 1 < ee, p2 = e + 2 < ee, p3 = e + 3 < ee;
        u32x2 v0, v1, v2, v3;
        if (p0) v0 = *(const u32x2*)(hsl + ((size_t)i0 << 7));
        if (p1) v1 = *(const u32x2*)(hsl + ((size_t)i1 << 7));
        if (p2) v2 = *(const u32x2*)(hsl + ((size_t)i2 << 7));
        if (p3) v3 = *(const u32x2*)(hsl + ((size_t)i3 << 7));
        if (p0) { acc_fp8x4(a0,     v0[0]); acc_fp8x4(a0 + 4, v0[1]); }
        if (p1) { acc_fp8x4(a1,     v1[0]); acc_fp8x4(a1 + 4, v1[1]); }
        if (p2) { acc_fp8x4(a0,     v2[0]); acc_fp8x4(a0 + 4, v2[1]); }
        if (p3) { acc_fp8x4(a1,     v3[0]); acc_fp8x4(a1 + 4, v3[1]); }
        e += 4;
    }

    {
        float di = nv ? dinv[nd] : 0.f;
        u32x4 o;
#pragma unroll
        for (int j = 0; j < 4; ++j) {
            unsigned lo = f2bf((a0[2 * j]     + a1[2 * j])     * di);
            unsigned hi = f2bf((a0[2 * j + 1] + a1[2 * j + 1]) * di);
            o[j] = lo | (hi << 16);
        }
        *(u32x4*)(&M[g][cs + li * 8]) = o;
    }
    __syncthreads();

    // ---- GEMM1: relu(m @ W1 + b1); wave computes 16 rows x 32 cols ----
    f32x4 acc[2];
    acc[0] = (f32x4){0.f, 0.f, 0.f, 0.f};
    acc[1] = (f32x4){0.f, 0.f, 0.f, 0.f};
#pragma unroll
    for (int k0 = 0; k0 < 128; k0 += 32) {
        s16x8 a = *(const s16x8*)(&M[l16][quad * 8 + k0]);
        s16x8 b0 = *(const s16x8*)(W1t + ((size_t)(cs + l16) << 7) + quad * 8 + k0);
        s16x8 b1 = *(const s16x8*)(W1t + ((size_t)(cs + 16 + l16) << 7) + quad * 8 + k0);
        acc[0] = __builtin_amdgcn_mfma_f32_16x16x32_bf16(a, b0, acc[0], 0, 0, 0);
        acc[1] = __builtin_amdgcn_mfma_f32_16x16x32_bf16(a, b1, acc[1], 0, 0, 0);
    }
#pragma unroll
    for (int c = 0; c < 2; ++c) {
        int col = cs + c * 16 + l16;
        float bv = B1[col];
#pragma unroll
        for (int reg = 0; reg < 4; ++reg) {
            float v = fmaxf(acc[c][reg] + bv, 0.f);
            P[quad * 4 + reg][col] = f2bf(v);
        }
    }
    __syncthreads();

    // ---- GEMM2: P @ W2 ----
    acc[0] = (f32x4){0.f, 0.f, 0.f, 0.f};
    acc[1] = (f32x4){0.f, 0.f, 0.f, 0.f};
#pragma unroll
    for (int k0 = 0; k0 < 128; k0 += 32) {
        s16x8 a = *(const s16x8*)(&P[l16][quad * 8 + k0]);
        s16x8 b0 = *(const s16x8*)(W2t + ((size_t)(cs + l16) << 7) + quad * 8 + k0);
        s16x8 b1 = *(const s16x8*)(W2t + ((size_t)(cs + 16 + l16) << 7) + quad * 8 + k0);
        acc[0] = __builtin_amdgcn_mfma_f32_16x16x32_bf16(a, b0, acc[0], 0, 0, 0);
        acc[1] = __builtin_amdgcn_mfma_f32_16x16x32_bf16(a, b1, acc[1], 0, 0, 0);
    }

    // ---- epilogue: residual + LN (cross-wave row sums via LDS partials) ----
    float z[2][4];
    float ps1[4] = {0, 0, 0, 0}, ps2[4] = {0, 0, 0, 0};
#pragma unroll
    for (int c = 0; c < 2; ++c) {
        int col = cs + c * 16 + l16;
        float b2v = B2[col];
#pragma unroll
        for (int reg = 0; reg < 4; ++reg) {
            int grow = r0 + quad * 4 + reg;
            float hv = (grow < N) ? bf2f(hin[((size_t)grow << 7) + col]) : 0.f;
            float zz = acc[c][reg] + b2v + hv;
            z[c][reg] = zz;
            ps1[reg] += zz;
            ps2[reg] += zz * zz;
        }
    }
#pragma unroll
    for (int off = 1; off < 16; off <<= 1) {
#pragma unroll
        for (int reg = 0; reg < 4; ++reg) {
            ps1[reg] += __shfl_xor(ps1[reg], off, 64);
            ps2[reg] += __shfl_xor(ps2[reg], off, 64);
        }
    }
    if (l16 == 0) {
#pragma unroll
        for (int reg = 0; reg < 4; ++reg) {
            s1p[s][quad * 4 + reg] = ps1[reg];
            s2p[s][quad * 4 + reg] = ps2[reg];
        }
    }
    __syncthreads();

#pragma unroll
    for (int reg = 0; reg < 4; ++reg) {
        int row = quad * 4 + reg;
        float S1 = s1p[0][row] + s1p[1][row] + s1p[2][row] + s1p[3][row];
        float S2 = s2p[0][row] + s2p[1][row] + s2p[2][row] + s2p[3][row];
        float mean = S1 * (1.0f / 128.0f);
        float var = S2 * (1.0f / 128.0f) - mean * mean;
        float rs = rsqrtf(var + LN_EPS);
        int grow = r0 + row;
        if (grow < N) {
#pragma unroll
            for (int c = 0; c < 2; ++c) {
                int col = cs + c * 16 + l16;
                float o = (z[c][reg] - mean) * rs * G[col] + Bb[col];
                if (out_f32) {
                    out_f32[((size_t)grow << 7) + col] = o;   // last layer: f32 only
                } else {
                    hout[((size_t)grow << 7) + col] = f2bf(o);
                    h8out[((size_t)grow << 7) + col] = f2fp8(o);
                }
            }
        }
    }
}

// ---------------- launch ----------------

extern "C" void kernel_launch(void* const* d_in, const int* in_sizes, int n_in,
                              void* d_out, int out_size, void* d_ws, size_t ws_size,
                              hipStream_t stream) {
    const float* x    = (const float*)d_in[0];
    const int*   ei   = (const int*)d_in[1];
    const float* in_w = (const float*)d_in[2];
    const float* in_b = (const float*)d_in[3];
    const float* w1   = (const float*)d_in[4];
    const float* b1   = (const float*)d_in[5];
    const float* w2   = (const float*)d_in[6];
    const float* b2   = (const float*)d_in[7];
    const float* ln_g = (const float*)d_in[8];
    const float* ln_b = (const float*)d_in[9];

    const int N = in_sizes[0] / DIM;               // 50000
    const int E = in_sizes[1] / 2;                 // 640000
    const int LAYERS = in_sizes[4] / (DIM * DIM);  // 3

    const int* e_src = ei;
    const int* e_dst = ei + E;

    // workspace layout
    char* ws = (char*)d_ws;
    unsigned short* hb0    = (unsigned short*)ws;  ws += (size_t)N * DIM * 2;
    unsigned short* hb1    = (unsigned short*)ws;  ws += (size_t)N * DIM * 2;
    unsigned char*  h8a    = (unsigned char*)ws;   ws += (size_t)N * DIM;
    unsigned char*  h8b    = (unsigned char*)ws;   ws += (size_t)N * DIM;
    int*            counts = (int*)ws;             ws += (size_t)N * 4;
    int*            rowptr = (int*)ws;             ws += (size_t)(N + 1) * 4;
    int*            cursor = (int*)ws;             ws += (size_t)N * 4;
    float*          dinv   = (float*)ws;           ws += (size_t)N * 4;
    int*            srcidx = (int*)ws;             ws += (size_t)E * 4;
    int*            bsum   = (int*)ws;             ws += 4096;
    int*            bofs   = (int*)ws;             ws += 4096;
    unsigned short* wt     = (unsigned short*)ws;  ws += (size_t)(2 * LAYERS + 1) * DIM * DIM * 2;

    const int nScanBlocks = (N + 1023) / 1024;
    const int nMat = 2 * LAYERS + 1;

    // --- CSR build (deg is layer-invariant) + weight conversion ---
    (void)hipMemsetAsync(counts, 0, (size_t)N * 4, stream);
    count_deg<<<(E + 255) / 256, 256, 0, stream>>>(e_dst, E, counts);
    scan_partials<<<nScanBlocks, 256, 0, stream>>>(counts, N, bsum);
    scan_bsums<<<1, 64, 0, stream>>>(bsum, bofs, nScanBlocks, rowptr, N, E);
    scan_final<<<nScanBlocks, 256, 0, stream>>>(counts, N, bofs, rowptr, cursor, dinv);
    fill_csr<<<(E + 255) / 256, 256, 0, stream>>>(e_src, e_dst, E, cursor, srcidx);
    cvt_weights<<<nMat * 8, 256, 0, stream>>>(in_w, w1, w2, wt, LAYERS);

    const unsigned short* in_wt = wt;
    const unsigned short* w1t   = wt + (size_t)DIM * DIM;
    const unsigned short* w2t   = wt + (size_t)(1 + LAYERS) * DIM * DIM;

    // --- input projection ---
    int tile_grid = (N + 15) / 16;
    gemm_bias_mfma<<<tile_grid, 256, 0, stream>>>(x, in_wt, in_b, hb0, h8a, N);

    // --- layers (ping-pong; gather reads pre-update fp8 table) ---
    unsigned short* hin  = hb0;  unsigned char* h8in  = h8a;
    unsigned short* hout = hb1;  unsigned char* h8out = h8b;
    for (int i = 0; i < LAYERS; ++i) {
        float* out = (i == LAYERS - 1) ? (float*)d_out : nullptr;
        agg_mlp_ln<<<tile_grid, 256, 0, stream>>>(hin, h8in, rowptr, srcidx, dinv,
                                                  w1t + (size_t)i * DIM * DIM, b1 + (size_t)i * DIM,
                                                  w2t + (size_t)i * DIM * DIM, b2 + (size_t)i * DIM,
                                                  ln_g + (size_t)i * DIM, ln_b + (size_t)i * DIM,
                                                  hout, h8out, out, N);
        unsigned short* t = hin; hin = hout; hout = t;
        unsigned char* t8 = h8in; h8in = h8out; h8out = t8;
    }
}